// Round 1
// baseline (158.067 us; speedup 1.0000x reference)
//
#include <hip/hip_runtime.h>
#include <hip/hip_bf16.h>

#define Bdim 2
#define Ldim 2048
#define Ddim 2048
#define Odim 2048
#define Edim 8
#define Kdim 2
#define NTOK (Bdim*Ldim)          // 4096
#define NSLOT (NTOK*Kdim)         // 8192
#define CAP NSLOT                 // per-expert perm capacity (worst case all slots)
#define BM 128
#define BN 128
#define BK 64
#define MAXMT (NSLOT/BM)          // 64 worst-case M-tiles per expert

typedef __attribute__((ext_vector_type(8))) short bf16x8;
typedef __attribute__((ext_vector_type(4))) float f32x4;
typedef __attribute__((ext_vector_type(8))) unsigned short ushort8;

// ---------------- f32 -> bf16 conversion (RNE) ----------------
__device__ __forceinline__ unsigned short f2bf(float f) {
  unsigned u = __builtin_bit_cast(unsigned, f);
  u += 0x7FFFu + ((u >> 16) & 1u);
  return (unsigned short)(u >> 16);
}

__global__ void cvt_kernel(const float* __restrict__ in,
                           unsigned short* __restrict__ out, int n8) {
  int i = blockIdx.x * blockDim.x + threadIdx.x;
  if (i >= n8) return;
  const float4* p = (const float4*)in;
  float4 a = p[2 * i];
  float4 b = p[2 * i + 1];
  ushort8 o;
  o[0] = f2bf(a.x); o[1] = f2bf(a.y); o[2] = f2bf(a.z); o[3] = f2bf(a.w);
  o[4] = f2bf(b.x); o[5] = f2bf(b.y); o[6] = f2bf(b.z); o[7] = f2bf(b.w);
  *(ushort8*)(out + 8 * (long)i) = o;
}

// ---------------- routing: build per-expert slot lists ----------------
__global__ void route_kernel(const int* __restrict__ idx,
                             int* __restrict__ perm, int* __restrict__ count) {
  __shared__ int cnt[Edim];
  int t = threadIdx.x;
  if (t < Edim) cnt[t] = 0;
  __syncthreads();
  for (int s = t; s < NSLOT; s += blockDim.x) {
    int e = idx[s];
    int pos = atomicAdd(&cnt[e], 1);
    perm[e * CAP + pos] = s;  // slot id; token = s >> 1, out row = s
  }
  __syncthreads();
  // pad each expert list to a multiple of BM with slot 0 (stores are masked)
  for (int e = 0; e < Edim; ++e) {
    int c = cnt[e];
    int pad = (c + BM - 1) & ~(BM - 1);
    for (int p = c + t; p < pad; p += blockDim.x) perm[e * CAP + p] = 0;
  }
  if (t < Edim) count[t] = cnt[t];
}

// ---------------- async global -> LDS, 16B per lane ----------------
__device__ __forceinline__ void gload_lds16(const unsigned short* g,
                                            unsigned short* l) {
  __builtin_amdgcn_global_load_lds(
      (const __attribute__((address_space(1))) void*)g,
      (__attribute__((address_space(3))) void*)l, 16, 0, 0);
}

// ---------------- grouped GEMM: out[s, :] = xb[tok] @ wb[e]^T + bias[e] ----
// A: gathered x rows (M x K, bf16, K contiguous); B: weight[e] (N x K = B^T form).
// LDS tiles are linear [rows][BK] but the 16B column slot is XOR-swizzled with
// (row&7) via pre-swizzled GLOBAL source addresses (global_load_lds writes
// linearly: base + lane*16). Reads apply the same XOR -> ~2-way conflicts.
__global__ __launch_bounds__(256) void moe_gemm(
    const unsigned short* __restrict__ xb, const unsigned short* __restrict__ wb,
    const float* __restrict__ bias, const int* __restrict__ perm,
    const int* __restrict__ count, float* __restrict__ out) {
  int e = blockIdx.y >> 6;   // / MAXMT
  int mt = blockIdx.y & 63;  // % MAXMT
  int ne = count[e];
  if (mt * BM >= ne) return;
  int nt = blockIdx.x;

  __shared__ unsigned short lA[BM * BK];  // 16 KiB
  __shared__ unsigned short lB[BN * BK];  // 16 KiB

  int tid = threadIdx.x;
  int wid = tid >> 6;
  int lane = tid & 63;
  int wr = wid >> 1, wc = wid & 1;  // 2x2 wave grid, 64x64 each

  // Staging: wave wid stages rows [wid*32, wid*32+32) of both tiles.
  // Chunk j (1 KiB) covers 8 rows; lane covers row (lane>>3), 16B slot (lane&7).
  // Pre-swizzle: source 16B-slot = (lane&7) ^ (row&7) = (lane&7)^(lane>>3).
  int srcCol = ((lane & 7) ^ (lane >> 3)) * 8;  // element offset within BK
  const unsigned short* aSrc[4];
  const unsigned short* bSrc[4];
  for (int j = 0; j < 4; ++j) {
    int r = wid * 32 + j * 8 + (lane >> 3);
    int s = perm[e * CAP + mt * BM + r];
    int tok = s >> 1;
    aSrc[j] = xb + (long)tok * Ddim + srcCol;
    bSrc[j] = wb + ((long)e * Odim + nt * BN + r) * Ddim + srcCol;
  }

  f32x4 acc[4][4];
  #pragma unroll
  for (int i = 0; i < 4; ++i)
    #pragma unroll
    for (int j = 0; j < 4; ++j) acc[i][j] = (f32x4){0.f, 0.f, 0.f, 0.f};

  for (int kt = 0; kt < Ddim / BK; ++kt) {
    #pragma unroll
    for (int j = 0; j < 4; ++j) {
      gload_lds16(aSrc[j] + kt * BK, &lA[(wid * 4 + j) * 512]);
      gload_lds16(bSrc[j] + kt * BK, &lB[(wid * 4 + j) * 512]);
    }
    __syncthreads();  // drains vmcnt (global_load_lds) + lgkm

    bf16x8 af[4][2], bf[4][2];
    #pragma unroll
    for (int mi = 0; mi < 4; ++mi) {
      int row = wr * 64 + mi * 16 + (lane & 15);
      #pragma unroll
      for (int kk = 0; kk < 2; ++kk) {
        int cs = kk * 4 + (lane >> 4);
        af[mi][kk] = *(const bf16x8*)&lA[row * BK + ((cs ^ (row & 7)) * 8)];
      }
    }
    #pragma unroll
    for (int ni = 0; ni < 4; ++ni) {
      int row = wc * 64 + ni * 16 + (lane & 15);
      #pragma unroll
      for (int kk = 0; kk < 2; ++kk) {
        int cs = kk * 4 + (lane >> 4);
        bf[ni][kk] = *(const bf16x8*)&lB[row * BK + ((cs ^ (row & 7)) * 8)];
      }
    }
    #pragma unroll
    for (int mi = 0; mi < 4; ++mi)
      #pragma unroll
      for (int ni = 0; ni < 4; ++ni)
        #pragma unroll
        for (int kk = 0; kk < 2; ++kk)
          acc[mi][ni] = __builtin_amdgcn_mfma_f32_16x16x32_bf16(
              af[mi][kk], bf[ni][kk], acc[mi][ni], 0, 0, 0);
    __syncthreads();  // protect LDS before next stage
  }

  // Epilogue: C/D layout col = lane&15, row = (lane>>4)*4 + j (guide §3, m89).
  int rowBase = mt * BM;
  #pragma unroll
  for (int mi = 0; mi < 4; ++mi) {
    int sIdx[4];
    bool ok[4];
    #pragma unroll
    for (int j = 0; j < 4; ++j) {
      int rloc = wr * 64 + mi * 16 + (lane >> 4) * 4 + j;
      ok[j] = (rowBase + rloc) < ne;
      sIdx[j] = ok[j] ? perm[e * CAP + rowBase + rloc] : 0;
    }
    #pragma unroll
    for (int ni = 0; ni < 4; ++ni) {
      int colG = nt * BN + wc * 64 + ni * 16 + (lane & 15);
      float bv = bias[e * Odim + colG];
      #pragma unroll
      for (int j = 0; j < 4; ++j) {
        if (ok[j]) out[(long)sIdx[j] * Odim + colG] = acc[mi][ni][j] + bv;
      }
    }
  }
}

extern "C" void kernel_launch(void* const* d_in, const int* in_sizes, int n_in,
                              void* d_out, int out_size, void* d_ws,
                              size_t ws_size, hipStream_t stream) {
  const float* x = (const float*)d_in[0];      // (B,L,D)
  const float* w = (const float*)d_in[1];      // (E,O,D)
  const float* bias = (const float*)d_in[2];   // (E,O)
  const int* idx = (const int*)d_in[3];        // (B,L,K)
  float* out = (float*)d_out;                  // (B,L,K,O)

  char* ws = (char*)d_ws;
  unsigned short* xb = (unsigned short*)ws;                          // 16 MiB
  unsigned short* wb = (unsigned short*)(ws + (size_t)16 * 1024 * 1024);  // 64 MiB
  int* perm = (int*)(ws + (size_t)80 * 1024 * 1024);                 // 256 KiB
  int* count = (int*)(ws + (size_t)80 * 1024 * 1024 + 256 * 1024);   // 32 B

  int n8x = Bdim * Ldim * Ddim / 8;  // 1,048,576
  int n8w = Edim * Odim * Ddim / 8;  // 4,194,304
  cvt_kernel<<<(n8x + 255) / 256, 256, 0, stream>>>(x, xb, n8x);
  cvt_kernel<<<(n8w + 255) / 256, 256, 0, stream>>>(w, wb, n8w);
  route_kernel<<<1, 1024, 0, stream>>>(idx, perm, count);
  moe_gemm<<<dim3(Odim / BN, Edim * MAXMT), 256, 0, stream>>>(xb, wb, bias, perm,
                                                              count, out);
}